// Round 10
// baseline (30.656 us; speedup 1.0000x reference)
//
#include <hip/hip_runtime.h>
#include <math.h>

// Problem constants (from reference)
#define BS 4
#define S 4096
#define H 32
#define KVH 8
#define HD 128
#define G 4            // H / KVH
#define WIN 1024
#define SCALE 0.08838834764831843f  // 1/sqrt(128)

// Flash-decoding split (R8 winning config)
#define NSPLIT 32
#define CHUNK (WIN / NSPLIT)   // 32 positions per block
#define PSTRIDE 132            // 128 out + m + l + 2 pad
#define WS_PART_OFF 256        // records start at float offset 256; counters below

// async global->LDS, 16B per lane, wave-uniform LDS base (+lane*16 by HW)
#define GLOAD_LDS16(gsrc, ldst) \
    __builtin_amdgcn_global_load_lds( \
        (const __attribute__((address_space(1))) void*)(gsrc), \
        (__attribute__((address_space(3))) void*)(ldst), 16, 0, 0)

// coherent-point (agent-scope, relaxed) accessors — sc0/sc1 path, no fences
#define ASTORE(p, v) __hip_atomic_store((p), (v), __ATOMIC_RELAXED, __HIP_MEMORY_SCOPE_AGENT)
#define ALOAD(p)     __hip_atomic_load((p), __ATOMIC_RELAXED, __HIP_MEMORY_SCOPE_AGENT)

// ---- DPP cross-lane reductions (VALU pipe, not DS) ----
template <int CTRL>
__device__ __forceinline__ float dpp_mov(float x) {
    return __int_as_float(__builtin_amdgcn_update_dpp(
        0, __float_as_int(x), CTRL, 0xF, 0xF, true));
}
__device__ __forceinline__ float red_add16(float d) {
    d += dpp_mov<0xB1>(d);
    d += dpp_mov<0x4E>(d);
    d += dpp_mov<0x124>(d);
    d += dpp_mov<0x128>(d);
    return d;   // all 16 lanes of each row hold the row sum
}
__device__ __forceinline__ float red_max16(float d) {
    d = fmaxf(d, dpp_mov<0xB1>(d));
    d = fmaxf(d, dpp_mov<0x4E>(d));
    d = fmaxf(d, dpp_mov<0x124>(d));
    d = fmaxf(d, dpp_mov<0x128>(d));
    return d;
}

// Fused: one block per (b, kvh, split). Phase A == R8 split kernel. Records are
// written with agent-scope atomic stores (visible at the device-coherent point
// without any L2-writeback fence); a relaxed agent atomicAdd counts completion;
// the last block per (b,kvh) reads all records via agent atomic loads and
// finalizes its 4 heads (+sink), writing the output. No second kernel.
__global__ __launch_bounds__(256) void attn_fused_kernel(
    const float* __restrict__ q, const float* __restrict__ k,
    const float* __restrict__ v, const float* __restrict__ mask,
    const float* __restrict__ sink, const int* __restrict__ start_positions,
    float* __restrict__ ws, float* __restrict__ out)
{
    const int blk   = blockIdx.x;
    const int split = blk % NSPLIT;
    const int kvh   = (blk / NSPLIT) % KVH;
    const int b     = blk / (NSPLIT * KVH);
    const int tid   = threadIdx.x;
    const int g     = tid >> 6;    // wave id == head-in-group
    const int lane  = tid & 63;
    const int grp   = lane >> 4;   // 0..3: position group (QK)
    const int l16   = lane & 15;   // dim slot within group
    const int h     = kvh * G + g;

    const int p = start_positions[b];             // last valid position
    const int base_pos = p - WIN + 1 + split * CHUNK;

    __shared__ float kbuf[CHUNK][HD];   // 16 KB
    __shared__ float vbuf[CHUNK][HD];   // 16 KB
    __shared__ float sc[G][CHUNK];      // per-wave score/e scratch
    __shared__ int last;

    const size_t kv_base = (size_t)b * S * (KVH * HD) + (size_t)kvh * HD;
    const int srow = lane >> 5;          // row within 1KB stripe
    const int scol = (lane & 31) * 4;    // float col within row

    // ---- stage K chunk: 16 stripes of 1KB (2 rows each), 4 stripes per wave ----
    #pragma unroll
    for (int i = 0; i < 4; ++i) {
        const int st  = g * 4 + i;
        const int r   = st * 2 + srow;
        const int pos = base_pos + r;
        const int row = (pos == p) ? (S - 1) : (pos < 0 ? 0 : pos);
        GLOAD_LDS16(k + kv_base + (size_t)row * (KVH * HD) + scol,
                    (char*)&kbuf[0][0] + st * 1024);
    }

    // mask for position (lane&31) of this chunk — off the QK critical path
    const int lpos = base_pos + (lane & 31);
    const float msk = (lpos >= 0) ? mask[(size_t)b * S + lpos] : 0.f;

    // q fragment: dims [l16*8, l16*8+8) of this head's last token
    const float* qptr = q + (((size_t)b * S + (S - 1)) * H + h) * HD + l16 * 8;
    const float4 qa = *(const float4*)(qptr);
    const float4 qb = *(const float4*)(qptr + 4);

    __syncthreads();   // K staged

    // ---- issue V staging NOW: fetch overlaps QK + softmax ----
    #pragma unroll
    for (int i = 0; i < 4; ++i) {
        const int st  = g * 4 + i;
        const int r   = st * 2 + srow;
        const int pos = base_pos + r;
        const int row = (pos == p) ? (S - 1) : (pos < 0 ? 0 : pos);
        GLOAD_LDS16(v + kv_base + (size_t)row * (KVH * HD) + scol,
                    (char*)&vbuf[0][0] + st * 1024);
    }

    // ---- QK from LDS: DPP 16-lane reductions ----
    #pragma unroll
    for (int it = 0; it < CHUNK / 4; ++it) {
        const int jj = it * 4 + grp;
        const float4 ka = *(const float4*)(&kbuf[jj][l16 * 8]);
        const float4 kb = *(const float4*)(&kbuf[jj][l16 * 8 + 4]);
        float d = qa.x * ka.x + qa.y * ka.y + qa.z * ka.z + qa.w * ka.w
                + qb.x * kb.x + qb.y * kb.y + qb.z * kb.z + qb.w * kb.w;
        d = red_add16(d);
        if (l16 == 0) sc[g][jj] = d;
    }

    // ---- partial softmax ----
    float s_l = sc[g][lane & (CHUNK - 1)] * SCALE + msk;
    if (lpos < 0) s_l = -1e30f;
    float m = red_max16(s_l);
    m = fmaxf(m, __shfl_xor(m, 16, 64));
    const float e_l = __expf(s_l - m);
    if (lane < CHUNK) sc[g][lane] = e_l;
    float lsum = red_add16(e_l);
    lsum += __shfl_xor(lsum, 16, 64);

    __syncthreads();   // V staged

    // ---- PV from LDS ----
    const int half = lane >> 5;
    const int l32  = lane & 31;
    float4 o4 = make_float4(0.f, 0.f, 0.f, 0.f);
    #pragma unroll
    for (int it = 0; it < CHUNK / 2; ++it) {
        const int jj = it * 2 + half;
        const float e = sc[g][jj];
        const float4 v4 = *(const float4*)(&vbuf[jj][l32 * 4]);
        o4.x += e * v4.x; o4.y += e * v4.y; o4.z += e * v4.z; o4.w += e * v4.w;
    }
    o4.x += __shfl_xor(o4.x, 32, 64);
    o4.y += __shfl_xor(o4.y, 32, 64);
    o4.z += __shfl_xor(o4.z, 32, 64);
    o4.w += __shfl_xor(o4.w, 32, 64);

    // ---- record store: agent-scope relaxed atomic dword stores (coherent point) ----
    const size_t widx = WS_PART_OFF +
        ((((size_t)b * KVH + kvh) * G + g) * NSPLIT + split) * (size_t)PSTRIDE;
    if (lane < 32) {
        ASTORE(&ws[widx + 4 * l32 + 0], o4.x);
        ASTORE(&ws[widx + 4 * l32 + 1], o4.y);
        ASTORE(&ws[widx + 4 * l32 + 2], o4.z);
        ASTORE(&ws[widx + 4 * l32 + 3], o4.w);
        if (lane == 0) { ASTORE(&ws[widx + 128], m); ASTORE(&ws[widx + 129], lsum); }
    }

    // ---- completion: drain stores (vmcnt(0) via syncthreads), relaxed counter ----
    asm volatile("s_waitcnt vmcnt(0)" ::: "memory");
    __syncthreads();
    if (tid == 0) {
        int* cnt = (int*)ws + (b * KVH + kvh);
        last = (__hip_atomic_fetch_add(cnt, 1, __ATOMIC_RELAXED,
                                       __HIP_MEMORY_SCOPE_AGENT) == NSPLIT - 1);
    }
    __syncthreads();
    if (!last) return;

    // ---- finalize (last block per (b,kvh)): wave g merges head h's 32 records ----
    const size_t fbase = WS_PART_OFF +
        ((((size_t)b * KVH + kvh) * G + g) * (size_t)NSPLIT) * (size_t)PSTRIDE;

    // lane j (<32) loads record j's m and l via coherent loads
    float mj = -1e30f, lj = 0.f;
    if (lane < NSPLIT) {
        mj = ALOAD(&ws[fbase + (size_t)lane * PSTRIDE + 128]);
        lj = ALOAD(&ws[fbase + (size_t)lane * PSTRIDE + 129]);
    }
    const float sk = sink[h];
    float M = red_max16(mj);
    M = fmaxf(M, __shfl_xor(M, 16, 64));
    M = fmaxf(M, __shfl_xor(M, 32, 64));
    M = fmaxf(M, sk);

    const float wj = (lane < NSPLIT) ? __expf(mj - M) : 0.f;
    float D = red_add16(wj * lj);
    D += __shfl_xor(D, 16, 64);
    D += __shfl_xor(D, 32, 64);
    D += __expf(sk - M);

    // lane owns dims {2*lane, 2*lane+1}; accumulate over the 32 records
    float ax = 0.f, ay = 0.f;
    #pragma unroll 8
    for (int i = 0; i < NSPLIT; ++i) {
        const float wi = __shfl(wj, i, 64);
        const size_t rec = fbase + (size_t)i * PSTRIDE;
        ax += wi * ALOAD(&ws[rec + 2 * lane]);
        ay += wi * ALOAD(&ws[rec + 2 * lane + 1]);
    }

    const float invD = 1.f / D;
    float2 r; r.x = ax * invD; r.y = ay * invD;
    *(float2*)(out + ((size_t)b * H + h) * HD + 2 * lane) = r;
}

extern "C" void kernel_launch(void* const* d_in, const int* in_sizes, int n_in,
                              void* d_out, int out_size, void* d_ws, size_t ws_size,
                              hipStream_t stream) {
    const float* q    = (const float*)d_in[0];
    const float* k    = (const float*)d_in[1];
    const float* v    = (const float*)d_in[2];
    // d_in[3] k_cache, d_in[4] v_cache, d_in[7] seq_block_ids: not needed — the
    // scatter-then-gather with injective page ids is the identity; last-token
    // overwrite handled by the row remap (pos==p -> S-1).
    const float* mask = (const float*)d_in[5];
    const float* sink = (const float*)d_in[6];
    const int* start_positions = (const int*)d_in[8];
    float* out = (float*)d_out;
    float* ws  = (float*)d_ws;   // counters: 32 ints at 0; records at +1KB (~532 KB)

    // zero the 32 completion counters (tiny graph-capturable memset node)
    hipMemsetAsync(d_ws, 0, BS * KVH * sizeof(int), stream);
    attn_fused_kernel<<<BS * KVH * NSPLIT, 256, 0, stream>>>(
        q, k, v, mask, sink, start_positions, ws, out);
}

// Round 11
// 14.232 us; speedup vs baseline: 2.1540x; 2.1540x over previous
//
#include <hip/hip_runtime.h>
#include <math.h>

// Problem constants (from reference)
#define BS 4
#define S 4096
#define H 32
#define KVH 8
#define HD 128
#define G 4            // H / KVH
#define WIN 1024
#define SCALE 0.08838834764831843f  // 1/sqrt(128)

// Flash-decoding split (R8 winning config)
#define NSPLIT 32
#define CHUNK (WIN / NSPLIT)   // 32 positions per block
#define PSTRIDE 132            // 128 out + m + l + 2 pad (keeps float4 alignment)

// async global->LDS, 16B per lane, wave-uniform LDS base (+lane*16 by HW)
#define GLOAD_LDS16(gsrc, ldst) \
    __builtin_amdgcn_global_load_lds( \
        (const __attribute__((address_space(1))) void*)(gsrc), \
        (__attribute__((address_space(3))) void*)(ldst), 16, 0, 0)

// wave-uniform float broadcast from a compile-time lane (VALU pipe, no DS)
#define READLANE_F(x, l) \
    __uint_as_float(__builtin_amdgcn_readlane(__float_as_uint(x), (l)))

// ---- DPP cross-lane reductions (VALU pipe, not DS) ----
// ctrl: 0xB1 = quad_perm(1,0,3,2) [xor1], 0x4E = quad_perm(2,3,0,1) [xor2],
//       0x124 = row_ror:4, 0x128 = row_ror:8 (within 16-lane row)
template <int CTRL>
__device__ __forceinline__ float dpp_mov(float x) {
    return __int_as_float(__builtin_amdgcn_update_dpp(
        0, __float_as_int(x), CTRL, 0xF, 0xF, true));
}
__device__ __forceinline__ float red_add16(float d) {
    d += dpp_mov<0xB1>(d);
    d += dpp_mov<0x4E>(d);
    d += dpp_mov<0x124>(d);
    d += dpp_mov<0x128>(d);
    return d;   // all 16 lanes of each row hold the row sum
}
__device__ __forceinline__ float red_max16(float d) {
    d = fmaxf(d, dpp_mov<0xB1>(d));
    d = fmaxf(d, dpp_mov<0x4E>(d));
    d = fmaxf(d, dpp_mov<0x124>(d));
    d = fmaxf(d, dpp_mov<0x128>(d));
    return d;
}

// Kernel 1: one block per (b, kvh, split). K staged into LDS before barrier 1;
// V staging issued after barrier 1 (fetch overlaps QK+softmax); barrier 2 drains
// V before PV. PV e-broadcast via v_readlane (VALU) instead of 32 LDS reads.
__global__ __launch_bounds__(256) void attn_split_kernel(
    const float* __restrict__ q, const float* __restrict__ k,
    const float* __restrict__ v, const float* __restrict__ mask,
    const int* __restrict__ start_positions, float* __restrict__ ws)
{
    const int blk   = blockIdx.x;
    const int split = blk % NSPLIT;
    const int kvh   = (blk / NSPLIT) % KVH;
    const int b     = blk / (NSPLIT * KVH);
    const int tid   = threadIdx.x;
    const int g     = tid >> 6;    // wave id == head-in-group
    const int lane  = tid & 63;
    const int grp   = lane >> 4;   // 0..3: position group (QK)
    const int l16   = lane & 15;   // dim slot within group
    const int h     = kvh * G + g;

    const int p = start_positions[b];             // last valid position
    const int base_pos = p - WIN + 1 + split * CHUNK;

    __shared__ float kbuf[CHUNK][HD];   // 16 KB
    __shared__ float vbuf[CHUNK][HD];   // 16 KB
    __shared__ float sc[G][CHUNK];      // per-wave raw-dot scratch

    const size_t kv_base = (size_t)b * S * (KVH * HD) + (size_t)kvh * HD;
    const int srow = lane >> 5;          // row within 1KB stripe
    const int scol = (lane & 31) * 4;    // float col within row

    // ---- stage K chunk: 16 stripes of 1KB (2 rows each), 4 stripes per wave ----
    #pragma unroll
    for (int i = 0; i < 4; ++i) {
        const int st  = g * 4 + i;       // stripe 0..15
        const int r   = st * 2 + srow;   // row within chunk
        const int pos = base_pos + r;
        const int row = (pos == p) ? (S - 1) : (pos < 0 ? 0 : pos);
        GLOAD_LDS16(k + kv_base + (size_t)row * (KVH * HD) + scol,
                    (char*)&kbuf[0][0] + st * 1024);
    }

    // mask for position (lane&31) of this chunk — off the QK critical path
    const int lpos = base_pos + (lane & 31);
    const float msk = (lpos >= 0) ? mask[(size_t)b * S + lpos] : 0.f;

    // q fragment: dims [l16*8, l16*8+8) of this head's last token
    const float* qptr = q + (((size_t)b * S + (S - 1)) * H + h) * HD + l16 * 8;
    const float4 qa = *(const float4*)(qptr);
    const float4 qb = *(const float4*)(qptr + 4);

    __syncthreads();   // K staged (drains K global_load_lds)

    // ---- issue V staging NOW: its HBM/L3 fetch overlaps QK + softmax below ----
    #pragma unroll
    for (int i = 0; i < 4; ++i) {
        const int st  = g * 4 + i;
        const int r   = st * 2 + srow;
        const int pos = base_pos + r;
        const int row = (pos == p) ? (S - 1) : (pos < 0 ? 0 : pos);
        GLOAD_LDS16(v + kv_base + (size_t)row * (KVH * HD) + scol,
                    (char*)&vbuf[0][0] + st * 1024);
    }

    // ---- QK from LDS: 8 iterations, 4 positions (one per group) in flight;
    //      16-lane reduction via DPP (VALU), raw dot -> sc ----
    #pragma unroll
    for (int it = 0; it < CHUNK / 4; ++it) {
        const int jj = it * 4 + grp;
        const float4 ka = *(const float4*)(&kbuf[jj][l16 * 8]);
        const float4 kb = *(const float4*)(&kbuf[jj][l16 * 8 + 4]);
        float d = qa.x * ka.x + qa.y * ka.y + qa.z * ka.z + qa.w * ka.w
                + qb.x * kb.x + qb.y * kb.y + qb.z * kb.z + qb.w * kb.w;
        d = red_add16(d);
        if (l16 == 0) sc[g][jj] = d;
    }

    // ---- partial softmax: all lanes hold position (lane&31)'s score ----
    float s_l = sc[g][lane & (CHUNK - 1)] * SCALE + msk;
    if (lpos < 0) s_l = -1e30f;
    float m = red_max16(s_l);
    m = fmaxf(m, __shfl_xor(m, 16, 64));          // combine rows -> 32-wide max
    const float e_l = __expf(s_l - m);            // e for position lane&31, all lanes
    float lsum = red_add16(e_l);
    lsum += __shfl_xor(lsum, 16, 64);

    __syncthreads();   // V staged (drains V global_load_lds)

    // ---- PV from LDS: 2 rows per iteration (half-wave each), float4 per lane;
    //      e scalars via v_readlane (VALU) + per-half cndmask — zero DS ops ----
    const int half = lane >> 5;
    const int l32  = lane & 31;
    float4 o4 = make_float4(0.f, 0.f, 0.f, 0.f);
    #pragma unroll
    for (int it = 0; it < CHUNK / 2; ++it) {
        const int jj = it * 2 + half;
        const float e0 = READLANE_F(e_l, it * 2);
        const float e1 = READLANE_F(e_l, it * 2 + 1);
        const float e  = half ? e1 : e0;
        const float4 v4 = *(const float4*)(&vbuf[jj][l32 * 4]);
        o4.x += e * v4.x; o4.y += e * v4.y; o4.z += e * v4.z; o4.w += e * v4.w;
    }
    o4.x += __shfl_xor(o4.x, 32, 64);
    o4.y += __shfl_xor(o4.y, 32, 64);
    o4.z += __shfl_xor(o4.z, 32, 64);
    o4.w += __shfl_xor(o4.w, 32, 64);

    const size_t widx = ((((size_t)b * KVH + kvh) * G + g) * NSPLIT + split) * (size_t)PSTRIDE;
    if (lane < 32) {
        *(float4*)(ws + widx + 4 * l32) = o4;
        if (lane == 0) {
            float2 ml; ml.x = m; ml.y = lsum;
            *(float2*)(ws + widx + 128) = ml;
        }
    }
}

// Kernel 2: one 256-thread block per (b, h). 4 waves x 8 splits each, two-phase
// LDS merge (block max, then weighted sums). (m,l) read as one float2.
__global__ __launch_bounds__(256) void attn_reduce_kernel(
    const float* __restrict__ ws, const float* __restrict__ sink,
    float* __restrict__ out)
{
    const int blk = blockIdx.x;    // b*H + h
    const int h = blk % H;
    const int b = blk / H;
    const int kvh = h / G;
    const int g = h % G;
    const int tid = threadIdx.x;
    const int w = tid >> 6;        // wave 0..3: handles splits [w*8, w*8+8)
    const int lane = tid & 63;

    const size_t base = ((((size_t)b * KVH + kvh) * G + g) * (size_t)NSPLIT) * (size_t)PSTRIDE;

    __shared__ float red_m[4];
    __shared__ float red_d[4];
    __shared__ float red_o[4][HD];

    const float sk = sink[h];

    // phase 1: per-wave max over its 8 partial maxima ((m,l) as float2)
    float2 ml[8];
    float Mw = -1e30f;
    #pragma unroll
    for (int i = 0; i < 8; ++i) {
        ml[i] = *(const float2*)(ws + base + (size_t)(w * 8 + i) * PSTRIDE + 128);
        Mw = fmaxf(Mw, ml[i].x);
    }
    if (lane == 0) red_m[w] = Mw;
    __syncthreads();
    float M = fmaxf(fmaxf(red_m[0], red_m[1]), fmaxf(red_m[2], red_m[3]));
    M = fmaxf(M, sk);

    // phase 2: per-wave weighted sums over its 8 records
    float D = 0.f, ax = 0.f, ay = 0.f;
    #pragma unroll
    for (int i = 0; i < 8; ++i) {
        const size_t rec = base + (size_t)(w * 8 + i) * PSTRIDE;
        const float wgt = __expf(ml[i].x - M);
        D += wgt * ml[i].y;
        const float2 o2 = *(const float2*)(ws + rec + 2 * lane);
        ax += wgt * o2.x;
        ay += wgt * o2.y;
    }
    if (lane == 0) red_d[w] = D;
    red_o[w][2 * lane]     = ax;
    red_o[w][2 * lane + 1] = ay;
    __syncthreads();

    // final combine + write by wave 0
    if (w == 0) {
        const float Dt = red_d[0] + red_d[1] + red_d[2] + red_d[3] + __expf(sk - M);
        const float ox = red_o[0][2 * lane] + red_o[1][2 * lane]
                       + red_o[2][2 * lane] + red_o[3][2 * lane];
        const float oy = red_o[0][2 * lane + 1] + red_o[1][2 * lane + 1]
                       + red_o[2][2 * lane + 1] + red_o[3][2 * lane + 1];
        const float invD = 1.f / Dt;
        float2 r; r.x = ox * invD; r.y = oy * invD;
        *(float2*)(out + ((size_t)b * H + h) * HD + 2 * lane) = r;
    }
}

extern "C" void kernel_launch(void* const* d_in, const int* in_sizes, int n_in,
                              void* d_out, int out_size, void* d_ws, size_t ws_size,
                              hipStream_t stream) {
    const float* q    = (const float*)d_in[0];
    const float* k    = (const float*)d_in[1];
    const float* v    = (const float*)d_in[2];
    // d_in[3] k_cache, d_in[4] v_cache, d_in[7] seq_block_ids: not needed for the
    // output — scatter-then-gather with injective page ids is the identity, and the
    // last-token overwrite is handled by the row remap (pos==p -> S-1).
    const float* mask = (const float*)d_in[5];
    const float* sink = (const float*)d_in[6];
    const int* start_positions = (const int*)d_in[8];
    float* out = (float*)d_out;
    float* ws  = (float*)d_ws;   // needs BS*KVH*G*NSPLIT*PSTRIDE*4 B ~= 2.2 MB

    attn_split_kernel<<<BS * KVH * NSPLIT, 256, 0, stream>>>(q, k, v, mask, start_positions, ws);
    attn_reduce_kernel<<<BS * H, 256, 0, stream>>>(ws, sink, out);
}